// Round 16
// baseline (332.607 us; speedup 1.0000x reference)
//
#include <hip/hip_runtime.h>
#include <hip/hip_bf16.h>
#include <stdint.h>

#define DEVI __device__ __forceinline__

typedef __attribute__((ext_vector_type(8)))  short bf16x8;
typedef __attribute__((ext_vector_type(4)))  short s16x4;
typedef __attribute__((ext_vector_type(4)))  float f32x4;
typedef __attribute__((ext_vector_type(16))) float f32x16;
typedef __attribute__((ext_vector_type(2)))  unsigned int u32x2;
typedef __attribute__((ext_vector_type(4)))  unsigned int u32x4;

#define L2E 1.44269504088896f

DEVI unsigned short f2bf(float f){
  union{float f; unsigned int u;} v; v.f = f;
  unsigned int u = v.u;
  u = u + 0x7FFFu + ((u >> 16) & 1u);
  return (unsigned short)(u >> 16);
}

DEVI unsigned int cvt_pk_bf16(float lo, float hi){
  unsigned int r;
  asm("v_cvt_pk_bf16_f32 %0, %1, %2" : "=v"(r) : "v"(lo), "v"(hi));
  return r;
}

typedef const __attribute__((address_space(1))) unsigned int gq_t;
typedef __attribute__((address_space(3))) unsigned int lq_t;

DEVI void gl_lds16(const unsigned short* g, unsigned short* l){
  __builtin_amdgcn_global_load_lds((gq_t*)(uintptr_t)g, (lq_t*)(uintptr_t)l, 16, 0, 0);
}

// ---------------- mask prep: detect u8 vs i32 bool layout, emit row lengths --
__global__ void prep_len(const unsigned char* mask, int* lens){
  __shared__ int nz, cnt0, cnt1;
  int tid = threadIdx.x;
  if(tid == 0){ nz = 0; cnt0 = 0; cnt1 = 0; }
  __syncthreads();
  int loc = 0;
  for(int i = tid; i < 4096; i += 256) loc |= mask[i];
  if(loc) atomicOr(&nz, 1);
  __syncthreads();
  bool isu8 = (nz != 0);
  const int* m32 = (const int*)mask;
  int c0 = 0, c1 = 0;
  for(int i = tid; i < 2048; i += 256){
    int p0 = isu8 ? (int)mask[i]        : m32[i];
    int p1 = isu8 ? (int)mask[2048 + i] : m32[2048 + i];
    c0 += (p0 == 0);
    c1 += (p1 == 0);
  }
  atomicAdd(&cnt0, c0);
  atomicAdd(&cnt1, c1);
  __syncthreads();
  if(tid == 0){ lens[0] = cnt0; lens[1] = cnt1; }
}

// ---------------- f32 -> bf16 weight conversion -----------------------------
__global__ void conv_bf16(const float* s, unsigned short* d, int n4){
  int i = blockIdx.x * 256 + threadIdx.x;
  if(i >= n4) return;
  f32x4 v = *(const f32x4*)(s + (size_t)i*4);
  s16x4 o;
  o[0]=(short)f2bf(v[0]); o[1]=(short)f2bf(v[1]);
  o[2]=(short)f2bf(v[2]); o[3]=(short)f2bf(v[3]);
  *(s16x4*)(d + (size_t)i*4) = o;
}

// ---------------- LayerNorm (one row of 1024 per block) ---------------------
__global__ __launch_bounds__(256)
void ln_k(const float* x, const float* g, const float* b, unsigned short* y){
  int row = blockIdx.x, tid = threadIdx.x;
  const float* xr = x + (size_t)row*1024;
  f32x4 v = *(const f32x4*)(xr + tid*4);
  float s = v[0]+v[1]+v[2]+v[3];
#pragma unroll
  for(int o=1;o<64;o<<=1) s += __shfl_xor(s, o, 64);
  __shared__ float red[8];
  if((tid & 63) == 0) red[tid>>6] = s;
  __syncthreads();
  float mean = (red[0]+red[1]+red[2]+red[3]) * 0.0009765625f;
  float d0=v[0]-mean, d1=v[1]-mean, d2=v[2]-mean, d3=v[3]-mean;
  float s2 = d0*d0 + d1*d1 + d2*d2 + d3*d3;
#pragma unroll
  for(int o=1;o<64;o<<=1) s2 += __shfl_xor(s2, o, 64);
  if((tid & 63) == 0) red[4 + (tid>>6)] = s2;
  __syncthreads();
  float var = (red[4]+red[5]+red[6]+red[7]) * 0.0009765625f;
  float rstd = rsqrtf(var + 1e-5f);
  f32x4 gg = *(const f32x4*)(g + tid*4);
  f32x4 bb = *(const f32x4*)(b + tid*4);
  s16x4 o;
  o[0] = (short)f2bf(d0*rstd*gg[0] + bb[0]);
  o[1] = (short)f2bf(d1*rstd*gg[1] + bb[1]);
  o[2] = (short)f2bf(d2*rstd*gg[2] + bb[2]);
  o[3] = (short)f2bf(d3*rstd*gg[3] + bb[3]);
  *(s16x4*)(y + (size_t)row*1024 + tid*4) = o;
}

// ---------------- GEMM: out[m][n] = sum_k X[m][k]*W[n][k] (+epilogue) -------
struct GemmP {
  const unsigned short* Wt;   // [Nmat][K] bf16
  const unsigned short* Xa;   // [4096][K] bf16
  int Nmat, K;
  const float* bias;          // [Nmat]
  const float* resid;         // f32 or null
  const int* lens;
  float* outF;
  unsigned short* outB;
};

template<int EPI, int NB, int KB>
__global__ __launch_bounds__(256)
void gemm_k(GemmP p){
  constexpr int NF = NB/32;              // n-frags per wave
  constexpr int CPR = KB/8;              // 16B chunks per LDS row
  constexpr int NW = (NB*KB)/2048;       // W staging issues per thread (bytes/4KB)
  constexpr int NX = (128*KB)/2048;      // X staging issues per thread
  __shared__ unsigned short lw[NB*KB];
  __shared__ unsigned short lx[128*KB];
  int nbn = p.Nmat / NB;
  int id = blockIdx.x;
  int cpx = gridDim.x >> 3;
  id = (id & 7)*cpx + (id >> 3);         // XCD swizzle (grid % 8 == 0)
  int bm = id / nbn, bn = id % nbn;
  int tid = threadIdx.x, lane = tid & 63, g = lane >> 4, l15 = lane & 15;
  int wave = tid >> 6, wm = wave & 1, wn = wave >> 1;

  const unsigned short* srcW[NW]; const unsigned short* srcX[NX];
  unsigned short* dstW[NW]; unsigned short* dstX[NX];
#pragma unroll
  for(int i=0;i<NW;++i){
    int slot = i*256 + tid, row = slot/CPR, c = slot%CPR, cs = c ^ (row & 7);
    srcW[i] = p.Wt + (size_t)(bn*NB + row)*p.K + cs*8;
    dstW[i] = lw + (i*256 + (tid & 192))*8;
  }
#pragma unroll
  for(int i=0;i<NX;++i){
    int slot = i*256 + tid, row = slot/CPR, c = slot%CPR, cs = c ^ (row & 7);
    srcX[i] = p.Xa + (size_t)(bm*128 + row)*p.K + cs*8;
    dstX[i] = lx + (i*256 + (tid & 192))*8;
  }

  f32x4 acc[NF][4];
#pragma unroll
  for(int a=0;a<NF;++a)
#pragma unroll
    for(int bb=0;bb<4;++bb)
#pragma unroll
      for(int e=0;e<4;++e) acc[a][bb][e] = 0.f;

  int iters = p.K / KB;
  for(int kt=0; kt<iters; ++kt){
#pragma unroll
    for(int i=0;i<NW;++i){
      gl_lds16(srcW[i], dstW[i]);
      srcW[i] += KB;
    }
#pragma unroll
    for(int i=0;i<NX;++i){
      gl_lds16(srcX[i], dstX[i]);
      srcX[i] += KB;
    }
    __syncthreads();
#pragma unroll
    for(int kc=0;kc<KB/32;++kc){
      bf16x8 af[NF], bfr[4];
#pragma unroll
      for(int nf=0;nf<NF;++nf){
        int row = wn*(16*NF) + nf*16 + l15;
        int ch = (kc*4 + g) ^ (row & 7);
        af[nf] = *(const bf16x8*)(lw + row*KB + ch*8);
      }
#pragma unroll
      for(int mf=0;mf<4;++mf){
        int row = wm*64 + mf*16 + l15;
        int ch = (kc*4 + g) ^ (row & 7);
        bfr[mf] = *(const bf16x8*)(lx + row*KB + ch*8);
      }
#pragma unroll
      for(int nf=0;nf<NF;++nf)
#pragma unroll
        for(int mf=0;mf<4;++mf)
          acc[nf][mf] = __builtin_amdgcn_mfma_f32_16x16x32_bf16(af[nf], bfr[mf], acc[nf][mf], 0, 0, 0);
    }
    __syncthreads();
  }

#pragma unroll
  for(int mf=0;mf<4;++mf){
    int m = bm*128 + wm*64 + mf*16 + l15;
#pragma unroll
    for(int nf=0;nf<NF;++nf){
      int n = bn*NB + wn*(16*NF) + nf*16 + g*4;
      f32x4 v = acc[nf][mf];
      f32x4 bz = *(const f32x4*)(p.bias + n);
      v = v + bz;
      if constexpr(EPI == 0){            // QKV: Q (cols<1024) *= L2E/8, bf16
        float sc = (n < 1024) ? 0.125f*L2E : 1.0f;
        s16x4 o;
#pragma unroll
        for(int e=0;e<4;++e) o[e] = (short)f2bf(v[e]*sc);
        *(s16x4*)(p.outB + (size_t)m*p.Nmat + n) = o;
      } else if constexpr(EPI == 1){     // out-proj: zero padded rows, +x, f32
        int b_ = m >> 11, q = m & 2047;
        f32x4 r = *(const f32x4*)(p.resid + (size_t)m*1024 + n);
        if(q >= p.lens[b_]){ v[0]=0.f; v[1]=0.f; v[2]=0.f; v[3]=0.f; }
        v = v + r;
        *(f32x4*)(p.outF + (size_t)m*p.Nmat + n) = v;
      } else if constexpr(EPI == 2){     // FFN1: quick-gelu, bf16
        s16x4 o;
#pragma unroll
        for(int e=0;e<4;++e){
          float sg = v[e]*__builtin_amdgcn_rcpf(1.f + exp2f(-1.702f*L2E*v[e]));
          o[e] = (short)f2bf(sg);
        }
        *(s16x4*)(p.outB + (size_t)m*p.Nmat + n) = o;
      } else {                           // FFN2: +x1, f32 out
        f32x4 r = *(const f32x4*)(p.resid + (size_t)m*p.Nmat + n);
        v = v + r;
        *(f32x4*)(p.outF + (size_t)m*p.Nmat + n) = v;
      }
    }
  }
}

// ---------------- V repack: qkv V-part [n][hd] -> vt [b,h,hd,n] -------------
__global__ __launch_bounds__(256)
void repack_vt(const unsigned short* qkv, unsigned short* vt){
  __shared__ unsigned short t[64*80];
  int id = blockIdx.x;
  int bh = id >> 5, nt = id & 31;
  int b = bh >> 4, h = bh & 15;
  int tid = threadIdx.x;
  int r = tid >> 2, c0 = (tid & 3)*16;
  const unsigned short* src = qkv + ((size_t)(b*2048 + nt*64 + r)*3072 + 2048 + h*64 + c0);
  bf16x8 v0 = *(const bf16x8*)(src);
  bf16x8 v1 = *(const bf16x8*)(src + 8);
  *(bf16x8*)(t + r*80 + c0) = v0;
  *(bf16x8*)(t + r*80 + c0 + 8) = v1;
  __syncthreads();
#pragma unroll
  for(int cc=0; cc<2; ++cc){
    int ci = cc*256 + tid;
    int hd = ci >> 3, nc = (ci & 7)*8;
    bf16x8 o;
#pragma unroll
    for(int i=0;i<8;++i) o[i] = (short)t[(nc+i)*80 + hd];
    *(bf16x8*)(vt + ((size_t)(bh*64 + hd)*2048 + nt*64 + nc)) = o;
  }
}

// ---------------- flash attention fwd: wave-independent tasks ---------------
// task = (bh, 32 q-rows). Each wave: private 16KB K/V LDS, no barriers,
// stage -> vmcnt(0) -> compute; stalls hidden by the other wave on the SIMD.
// grid 512 x 4 waves = 2048 tasks; blocks uniform (4 waves share j, diff bh);
// dispatch pairs j with 63-j across the two scheduling rounds.
__global__ __launch_bounds__(256)
void attn_flash(const unsigned short* qkv, const unsigned short* vt,
                unsigned short* attnO, float* mrow, float* lrow, const int* lens)
{
  __shared__ unsigned short lk[4][64*64];
  __shared__ unsigned short lv[4][64*64];
  int id = blockIdx.x;
  int wave = threadIdx.x >> 6, lane = threadIdx.x & 63;
  int hi = lane >> 5, l31 = lane & 31;
  int j = (id < 256) ? (63 - (id >> 3)) : ((id - 256) >> 3);
  int bh = (id & 7)*4 + wave;
  int b = bh >> 4, h = bh & 15;
  int q = j*32 + l31;
  int len_b = lens[b];
  int ntiles = (j + 2) >> 1;

  const unsigned short* qptr = qkv + ((size_t)(b*2048 + q)*3072 + h*64);
  bf16x8 qf[4];
#pragma unroll
  for(int ks=0;ks<4;++ks) qf[ks] = *(const bf16x8*)(qptr + ks*16 + hi*8);

  // staging: issue i covers rows i*8..i*8+7; chunk c = lane&7, row-lane = lane>>3
  int cs = (lane & 7) ^ (lane >> 3);     // swizzled source chunk (tile-invariant)
  const unsigned short* kSrc = qkv + ((size_t)(b*2048 + (lane>>3))*3072 + 1024 + h*64) + cs*8;
  const unsigned short* vSrc = vt + ((size_t)(bh*64 + (lane>>3))*2048) + cs*8;
  unsigned short* kDst = &lk[wave][0];
  unsigned short* vDst = &lv[wave][0];

  f32x16 oacc[2];
#pragma unroll
  for(int a=0;a<2;++a)
#pragma unroll
    for(int e=0;e<16;++e) oacc[a][e] = 0.f;
  float mcur = -1e30f, lsum = 0.f;

  for(int t=0; t<ntiles; ++t){
    // stage tile t into private buffers (16 loads), then wait
#pragma unroll
    for(int i=0;i<8;++i){
      gl_lds16(kSrc + (size_t)i*8*3072, kDst + i*512);
      gl_lds16(vSrc + (size_t)i*8*2048, vDst + i*512);
    }
    kSrc += (size_t)64*3072;
    vSrc += 64;
    asm volatile("s_waitcnt vmcnt(0)" ::: "memory");

    f32x16 s2[2];
    __builtin_amdgcn_s_setprio(1);
#pragma unroll
    for(int kb=0;kb<2;++kb){
      f32x16 a;
#pragma unroll
      for(int e=0;e<16;++e) a[e] = 0.f;
      int row = kb*32 + l31;
#pragma unroll
      for(int ks=0;ks<4;++ks){
        int ch = (ks*2 + hi) ^ (row & 7);
        bf16x8 kf = *(const bf16x8*)(kDst + row*64 + ch*8);
        a = __builtin_amdgcn_mfma_f32_32x32x16_bf16(kf, qf[ks], a, 0, 0, 0);
      }
      s2[kb] = a;
    }
    __builtin_amdgcn_s_setprio(0);

    // masking + max: 4-acc tree
    float m0=-1e30f, m1=-1e30f, m2=-1e30f, m3=-1e30f;
    bool full = (t*64 + 63 < j*32) && (t*64 + 64 <= len_b);
    if(full){
#pragma unroll
      for(int kb=0;kb<2;++kb)
#pragma unroll
        for(int r=0;r<16;r+=4){
          m0=fmaxf(m0,s2[kb][r+0]); m1=fmaxf(m1,s2[kb][r+1]);
          m2=fmaxf(m2,s2[kb][r+2]); m3=fmaxf(m3,s2[kb][r+3]);
        }
    } else {
#pragma unroll
      for(int kb=0;kb<2;++kb)
#pragma unroll
        for(int r=0;r<16;++r){
          int key = t*64 + kb*32 + (r&3) + 8*(r>>2) + 4*hi;
          bool ok = (key == q) || ((key < q) && (key < len_b));
          float tv = ok ? s2[kb][r] : -1e30f;
          s2[kb][r] = tv;
          if((r&3)==0) m0=fmaxf(m0,tv); else if((r&3)==1) m1=fmaxf(m1,tv);
          else if((r&3)==2) m2=fmaxf(m2,tv); else m3=fmaxf(m3,tv);
        }
    }
    float tmax = fmaxf(fmaxf(m0,m1), fmaxf(m2,m3));
    tmax = fmaxf(tmax, __shfl_xor(tmax, 32, 64));

    if(!__all(tmax <= mcur + 8.f)){      // defer-max (T13)
      float mnew = fmaxf(mcur, tmax);
      float fsc = exp2f(mcur - mnew);
      lsum *= fsc;
#pragma unroll
      for(int a=0;a<2;++a)
#pragma unroll
        for(int e=0;e<16;++e) oacc[a][e] *= fsc;
      mcur = mnew;
    }
    float r0=0.f, r1=0.f, r2=0.f, r3=0.f;
#pragma unroll
    for(int kb=0;kb<2;++kb)
#pragma unroll
      for(int r=0;r<16;++r){
        float pv = exp2f(s2[kb][r] - mcur);
        s2[kb][r] = pv;
        if((r&3)==0) r0+=pv; else if((r&3)==1) r1+=pv;
        else if((r&3)==2) r2+=pv; else r3+=pv;
      }
    float rsum = (r0+r1)+(r2+r3);
    rsum += __shfl_xor(rsum, 32, 64);
    lsum += rsum;

    __builtin_amdgcn_s_setprio(1);
#pragma unroll
    for(int ks=0;ks<4;++ks){
      int kb = ks >> 1, r0i = (ks & 1)*8;
      unsigned int a0 = cvt_pk_bf16(s2[kb][r0i+0], s2[kb][r0i+1]);
      unsigned int a1 = cvt_pk_bf16(s2[kb][r0i+2], s2[kb][r0i+3]);
      unsigned int a2 = cvt_pk_bf16(s2[kb][r0i+4], s2[kb][r0i+5]);
      unsigned int a3 = cvt_pk_bf16(s2[kb][r0i+6], s2[kb][r0i+7]);
      unsigned int b0 = __shfl_xor(a0, 32, 64);
      unsigned int b1 = __shfl_xor(a1, 32, 64);
      unsigned int b2 = __shfl_xor(a2, 32, 64);
      unsigned int b3 = __shfl_xor(a3, 32, 64);
      union { u32x4 u; bf16x8 s8; } pw;
      pw.u[0] = hi ? b2 : a0;
      pw.u[1] = hi ? b3 : a1;
      pw.u[2] = hi ? a2 : b0;
      pw.u[3] = hi ? a3 : b1;
#pragma unroll
      for(int af=0;af<2;++af){
        int vrow = af*32 + l31;
        int ch = (ks*2 + hi) ^ (vrow & 7);
        bf16x8 vf = *(const bf16x8*)(vDst + vrow*64 + ch*8);
        oacc[af] = __builtin_amdgcn_mfma_f32_32x32x16_bf16(vf, pw.s8, oacc[af], 0, 0, 0);
      }
    }
    __builtin_amdgcn_s_setprio(0);
    // tile-t LDS reads retired before next stage overwrites (WAR, wave-private)
    asm volatile("s_waitcnt lgkmcnt(0)" ::: "memory");
  }

  float rl = __builtin_amdgcn_rcpf(lsum);
  if(hi == 0){
    mrow[(size_t)bh*2048 + q] = mcur;
    lrow[(size_t)bh*2048 + q] = lsum;
  }
  unsigned short* obase = attnO + ((size_t)(b*2048 + q)*1024 + h*64);
#pragma unroll
  for(int af=0;af<2;++af)
#pragma unroll
    for(int grp=0; grp<4; ++grp){
      int hd0 = af*32 + grp*8 + hi*4;
      u32x2 st;
      st[0] = cvt_pk_bf16(oacc[af][grp*4+0]*rl, oacc[af][grp*4+1]*rl);
      st[1] = cvt_pk_bf16(oacc[af][grp*4+2]*rl, oacc[af][grp*4+3]*rl);
      *(u32x2*)(obase + hd0) = st;
    }
}

// ---------------- c = 2^-m / l per (b,h,q) ----------------------------------
__global__ void prep_c(const float* mrow, const float* lrow, float* cbuf){
  int i = blockIdx.x*256 + threadIdx.x;
  cbuf[i] = exp2f(-mrow[i]) * __builtin_amdgcn_rcpf(lrow[i]);
}

// ---------------- weights = mean_h softmax probs (recompute QK^T) -----------
__global__ __launch_bounds__(256)
void attn_weights(const unsigned short* qkv, const float* cbuf,
                  float* wout, const int* lens)
{
  int id = blockIdx.x;
  int kt = id & 15, qt = (id >> 4) & 15, b = id >> 8;
  int tid = threadIdx.x;
  float* wtile = wout + ((size_t)(b*2048 + qt*128))*2048 + kt*128;

  if(kt > qt){                            // strictly-upper tile: zeros
    f32x4 z; z[0]=0.f; z[1]=0.f; z[2]=0.f; z[3]=0.f;
#pragma unroll
    for(int i=0;i<8;++i){
      float* p = wtile + (size_t)(i*16 + (tid>>4))*2048 + (tid&15)*8;
      *(f32x4*)p = z; *(f32x4*)(p+4) = z;
    }
    return;
  }

  __shared__ unsigned short lk[2][128*64];
  __shared__ unsigned short lq[2][128*64];
  int lane = tid & 63, wave = tid >> 6, hi = lane >> 5, l31 = lane & 31;
  int len_b = lens[b];
  int q_abs = qt*128 + wave*32 + l31;

  const float* cb = cbuf + (size_t)(b*16)*2048 + q_abs;
  float ccs[16];
#pragma unroll
  for(int h=0;h<16;++h) ccs[h] = cb[(size_t)h*2048];

  const unsigned short* srcK[4]; const unsigned short* srcQ[4]; int dA[4];
#pragma unroll
  for(int i=0;i<4;++i){
    int d = i*256 + tid, row = d >> 3, c = d & 7, cs = c ^ (row & 7);
    srcK[i] = qkv + ((size_t)(b*2048 + kt*128 + row)*3072 + 1024) + cs*8;
    srcQ[i] = qkv + ((size_t)(b*2048 + qt*128 + row)*3072) + cs*8;
    dA[i] = d*8;
  }

  float wacc[4][16];
#pragma unroll
  for(int ksub=0;ksub<4;++ksub)
#pragma unroll
    for(int r=0;r<16;++r) wacc[ksub][r] = 0.f;

#pragma unroll
  for(int i=0;i<4;++i){
    gl_lds16(srcK[i], &lk[0][dA[i]]);
    gl_lds16(srcQ[i], &lq[0][dA[i]]);
  }
  __syncthreads();

  int buf = 0;
  for(int h=0;h<16;++h){
    if(h < 15){
#pragma unroll
      for(int i=0;i<4;++i){
        gl_lds16(srcK[i] + (h+1)*64, &lk[buf^1][dA[i]]);
        gl_lds16(srcQ[i] + (h+1)*64, &lq[buf^1][dA[i]]);
      }
    }
    bf16x8 qf[4];
#pragma unroll
    for(int ks=0;ks<4;++ks){
      int row = wave*32 + l31;
      int ch = (ks*2 + hi) ^ (row & 7);
      qf[ks] = *(const bf16x8*)(&lq[buf][0] + row*64 + ch*8);
    }
    float cc = ccs[h];
#pragma unroll
    for(int ksub=0;ksub<4;++ksub){
      f32x16 sc;
#pragma unroll
      for(int e=0;e<16;++e) sc[e] = 0.f;
#pragma unroll
      for(int ks=0;ks<4;++ks){
        int row = ksub*32 + l31;
        int ch = (ks*2 + hi) ^ (row & 7);
        bf16x8 kf = *(const bf16x8*)(&lk[buf][0] + row*64 + ch*8);
        sc = __builtin_amdgcn_mfma_f32_32x32x16_bf16(kf, qf[ks], sc, 0, 0, 0);
      }
#pragma unroll
      for(int r=0;r<16;++r)
        wacc[ksub][r] += exp2f(sc[r]) * cc;  // Q pre-scaled by L2E
    }
    __syncthreads();
    buf ^= 1;
  }

#pragma unroll
  for(int ksub=0;ksub<4;++ksub)
#pragma unroll
    for(int rg=0;rg<4;++rg){
      f32x4 v;
#pragma unroll
      for(int e=0;e<4;++e){
        int key_abs = kt*128 + ksub*32 + rg*8 + hi*4 + e;
        bool ok = (key_abs == q_abs) || ((key_abs < q_abs) && (key_abs < len_b));
        v[e] = ok ? wacc[ksub][rg*4 + e]*0.0625f : 0.f;
      }
      *(f32x4*)(wtile + (size_t)(wave*32 + l31)*2048 + ksub*32 + rg*8 + hi*4) = v;
    }
}

// ---------------- launch --------------------------------------------------
extern "C" void kernel_launch(void* const* d_in, const int* in_sizes, int n_in,
                              void* d_out, int out_size, void* d_ws, size_t ws_size,
                              hipStream_t stream)
{
  const float* x     = (const float*)d_in[0];
  const unsigned char* mask = (const unsigned char*)d_in[1];
  const float* ln1g  = (const float*)d_in[2];
  const float* ln1b  = (const float*)d_in[3];
  const float* w_in  = (const float*)d_in[4];
  const float* b_in  = (const float*)d_in[5];
  const float* w_out = (const float*)d_in[6];
  const float* b_out = (const float*)d_in[7];
  const float* ln2g  = (const float*)d_in[8];
  const float* ln2b  = (const float*)d_in[9];
  const float* w1    = (const float*)d_in[10];
  const float* b1    = (const float*)d_in[11];
  const float* w2    = (const float*)d_in[12];
  const float* b2    = (const float*)d_in[13];
  float* out = (float*)d_out;

  char* ws = (char*)d_ws;
  size_t off = 0;
  auto take = [&](size_t bytes)->char*{
    char* p = ws + off; off += (bytes + 255) & ~(size_t)255; return p;
  };
  int* lens            = (int*)take(256);
  unsigned short* wq   = (unsigned short*)take((size_t)3072*1024*2);
  unsigned short* wo   = (unsigned short*)take((size_t)1024*1024*2);
  unsigned short* w1c  = (unsigned short*)take((size_t)4096*1024*2);
  unsigned short* w2c  = (unsigned short*)take((size_t)1024*4096*2);
  unsigned short* xn   = (unsigned short*)take((size_t)4096*1024*2);
  unsigned short* qkv  = (unsigned short*)take((size_t)4096*3072*2);
  unsigned short* vt   = (unsigned short*)take((size_t)32*64*2048*2);
  float* mrow          = (float*)take((size_t)32*2048*4);
  float* lrow          = (float*)take((size_t)32*2048*4);
  float* cbuf          = (float*)take((size_t)32*2048*4);
  unsigned short* aO   = (unsigned short*)take((size_t)4096*1024*2);
  float* x1            = (float*)take((size_t)4096*1024*4);
  unsigned short* hmid = (unsigned short*)take((size_t)4096*4096*2);

  prep_len<<<1,256,0,stream>>>(mask, lens);
  conv_bf16<<<3072,256,0,stream>>>(w_in, wq, 786432);
  conv_bf16<<<1024,256,0,stream>>>(w_out, wo, 262144);
  conv_bf16<<<4096,256,0,stream>>>(w1, w1c, 1048576);
  conv_bf16<<<4096,256,0,stream>>>(w2, w2c, 1048576);
  ln_k<<<4096,256,0,stream>>>(x, ln1g, ln1b, xn);

  GemmP p1{wq, xn, 3072, 1024, b_in, nullptr, nullptr, nullptr, qkv};
  gemm_k<0,128,64><<<768,256,0,stream>>>(p1);
  repack_vt<<<1024,256,0,stream>>>(qkv, vt);
  attn_flash<<<512,256,0,stream>>>(qkv, vt, aO, mrow, lrow, lens);
  prep_c<<<256,256,0,stream>>>(mrow, lrow, cbuf);
  attn_weights<<<512,256,0,stream>>>(qkv, cbuf, out + 4194304, lens);

  GemmP p2{wo, aO, 1024, 1024, b_out, x, lens, x1, nullptr};
  gemm_k<1,64,128><<<512,256,0,stream>>>(p2);
  ln_k<<<4096,256,0,stream>>>(x1, ln2g, ln2b, xn);
  GemmP p3{w1c, xn, 4096, 1024, b1, nullptr, nullptr, nullptr, hmid};
  gemm_k<2,128,64><<<1024,256,0,stream>>>(p3);
  GemmP p4{w2c, hmid, 1024, 4096, b2, x1, nullptr, out, nullptr};
  gemm_k<3,64,128><<<512,256,0,stream>>>(p4);
}

// Round 17
// 313.916 us; speedup vs baseline: 1.0595x; 1.0595x over previous
//
#include <hip/hip_runtime.h>
#include <hip/hip_bf16.h>
#include <stdint.h>

#define DEVI __device__ __forceinline__

typedef __attribute__((ext_vector_type(8)))  short bf16x8;
typedef __attribute__((ext_vector_type(4)))  short s16x4;
typedef __attribute__((ext_vector_type(4)))  float f32x4;
typedef __attribute__((ext_vector_type(16))) float f32x16;
typedef __attribute__((ext_vector_type(2)))  unsigned int u32x2;
typedef __attribute__((ext_vector_type(4)))  unsigned int u32x4;

#define L2E 1.44269504088896f

DEVI unsigned short f2bf(float f){
  union{float f; unsigned int u;} v; v.f = f;
  unsigned int u = v.u;
  u = u + 0x7FFFu + ((u >> 16) & 1u);
  return (unsigned short)(u >> 16);
}

DEVI unsigned int cvt_pk_bf16(float lo, float hi){
  unsigned int r;
  asm("v_cvt_pk_bf16_f32 %0, %1, %2" : "=v"(r) : "v"(lo), "v"(hi));
  return r;
}

typedef const __attribute__((address_space(1))) unsigned int gq_t;
typedef __attribute__((address_space(3))) unsigned int lq_t;

DEVI void gl_lds16(const unsigned short* g, unsigned short* l){
  __builtin_amdgcn_global_load_lds((gq_t*)(uintptr_t)g, (lq_t*)(uintptr_t)l, 16, 0, 0);
}

// ---------------- mask prep: detect u8 vs i32 bool layout, emit row lengths --
__global__ void prep_len(const unsigned char* mask, int* lens){
  __shared__ int nz, cnt0, cnt1;
  int tid = threadIdx.x;
  if(tid == 0){ nz = 0; cnt0 = 0; cnt1 = 0; }
  __syncthreads();
  int loc = 0;
  for(int i = tid; i < 4096; i += 256) loc |= mask[i];
  if(loc) atomicOr(&nz, 1);
  __syncthreads();
  bool isu8 = (nz != 0);
  const int* m32 = (const int*)mask;
  int c0 = 0, c1 = 0;
  for(int i = tid; i < 2048; i += 256){
    int p0 = isu8 ? (int)mask[i]        : m32[i];
    int p1 = isu8 ? (int)mask[2048 + i] : m32[2048 + i];
    c0 += (p0 == 0);
    c1 += (p1 == 0);
  }
  atomicAdd(&cnt0, c0);
  atomicAdd(&cnt1, c1);
  __syncthreads();
  if(tid == 0){ lens[0] = cnt0; lens[1] = cnt1; }
}

// ---------------- fused f32 -> bf16 weight conversion (4 ranges, dst contig) -
__global__ void conv_all(const float* s0, const float* s1, const float* s2,
                         const float* s3, unsigned short* d){
  int i = blockIdx.x*256 + threadIdx.x;   // quad index, total 3145728
  const float* s; int off;
  if(i < 786432){ s = s0; off = 0; }
  else if(i < 1048576){ s = s1; off = 786432; }
  else if(i < 2097152){ s = s2; off = 1048576; }
  else { s = s3; off = 2097152; }
  f32x4 v = *(const f32x4*)(s + (size_t)(i - off)*4);
  s16x4 o;
  o[0]=(short)f2bf(v[0]); o[1]=(short)f2bf(v[1]);
  o[2]=(short)f2bf(v[2]); o[3]=(short)f2bf(v[3]);
  *(s16x4*)(d + (size_t)i*4) = o;
}

// ---------------- LayerNorm (one row of 1024 per block) ---------------------
__global__ __launch_bounds__(256)
void ln_k(const float* x, const float* g, const float* b, unsigned short* y){
  int row = blockIdx.x, tid = threadIdx.x;
  const float* xr = x + (size_t)row*1024;
  f32x4 v = *(const f32x4*)(xr + tid*4);
  float s = v[0]+v[1]+v[2]+v[3];
#pragma unroll
  for(int o=1;o<64;o<<=1) s += __shfl_xor(s, o, 64);
  __shared__ float red[8];
  if((tid & 63) == 0) red[tid>>6] = s;
  __syncthreads();
  float mean = (red[0]+red[1]+red[2]+red[3]) * 0.0009765625f;
  float d0=v[0]-mean, d1=v[1]-mean, d2=v[2]-mean, d3=v[3]-mean;
  float s2 = d0*d0 + d1*d1 + d2*d2 + d3*d3;
#pragma unroll
  for(int o=1;o<64;o<<=1) s2 += __shfl_xor(s2, o, 64);
  if((tid & 63) == 0) red[4 + (tid>>6)] = s2;
  __syncthreads();
  float var = (red[4]+red[5]+red[6]+red[7]) * 0.0009765625f;
  float rstd = rsqrtf(var + 1e-5f);
  f32x4 gg = *(const f32x4*)(g + tid*4);
  f32x4 bb = *(const f32x4*)(b + tid*4);
  s16x4 o;
  o[0] = (short)f2bf(d0*rstd*gg[0] + bb[0]);
  o[1] = (short)f2bf(d1*rstd*gg[1] + bb[1]);
  o[2] = (short)f2bf(d2*rstd*gg[2] + bb[2]);
  o[3] = (short)f2bf(d3*rstd*gg[3] + bb[3]);
  *(s16x4*)(y + (size_t)row*1024 + tid*4) = o;
}

// ---------------- GEMM: out[m][n] = sum_k X[m][k]*W[n][k] (+epilogue) -------
struct GemmP {
  const unsigned short* Wt;   // [Nmat][K] bf16
  const unsigned short* Xa;   // [4096][K] bf16
  int Nmat, K;
  const float* bias;          // [Nmat]
  const float* resid;         // f32 or null
  const int* lens;
  float* outF;
  unsigned short* outB;
};

template<int EPI, int NB, int KB>
__global__ __launch_bounds__(256)
void gemm_k(GemmP p){
  constexpr int NF = NB/32;              // n-frags per wave
  constexpr int CPR = KB/8;              // 16B chunks per LDS row
  constexpr int NW = (NB*KB)/2048;       // W staging issues per thread (bytes/4KB)
  constexpr int NX = (128*KB)/2048;      // X staging issues per thread
  __shared__ unsigned short lw[NB*KB];
  __shared__ unsigned short lx[128*KB];
  int nbn = p.Nmat / NB;
  int id = blockIdx.x;
  int cpx = gridDim.x >> 3;
  id = (id & 7)*cpx + (id >> 3);         // XCD swizzle (grid % 8 == 0)
  int bm = id / nbn, bn = id % nbn;
  int tid = threadIdx.x, lane = tid & 63, g = lane >> 4, l15 = lane & 15;
  int wave = tid >> 6, wm = wave & 1, wn = wave >> 1;

  const unsigned short* srcW[NW]; const unsigned short* srcX[NX];
  unsigned short* dstW[NW]; unsigned short* dstX[NX];
#pragma unroll
  for(int i=0;i<NW;++i){
    int slot = i*256 + tid, row = slot/CPR, c = slot%CPR, cs = c ^ (row & 7);
    srcW[i] = p.Wt + (size_t)(bn*NB + row)*p.K + cs*8;
    dstW[i] = lw + (i*256 + (tid & 192))*8;
  }
#pragma unroll
  for(int i=0;i<NX;++i){
    int slot = i*256 + tid, row = slot/CPR, c = slot%CPR, cs = c ^ (row & 7);
    srcX[i] = p.Xa + (size_t)(bm*128 + row)*p.K + cs*8;
    dstX[i] = lx + (i*256 + (tid & 192))*8;
  }

  f32x4 acc[NF][4];
#pragma unroll
  for(int a=0;a<NF;++a)
#pragma unroll
    for(int bb=0;bb<4;++bb)
#pragma unroll
      for(int e=0;e<4;++e) acc[a][bb][e] = 0.f;

  int iters = p.K / KB;
  for(int kt=0; kt<iters; ++kt){
#pragma unroll
    for(int i=0;i<NW;++i){
      gl_lds16(srcW[i], dstW[i]);
      srcW[i] += KB;
    }
#pragma unroll
    for(int i=0;i<NX;++i){
      gl_lds16(srcX[i], dstX[i]);
      srcX[i] += KB;
    }
    __syncthreads();
#pragma unroll
    for(int kc=0;kc<KB/32;++kc){
      bf16x8 af[NF], bfr[4];
#pragma unroll
      for(int nf=0;nf<NF;++nf){
        int row = wn*(16*NF) + nf*16 + l15;
        int ch = (kc*4 + g) ^ (row & 7);
        af[nf] = *(const bf16x8*)(lw + row*KB + ch*8);
      }
#pragma unroll
      for(int mf=0;mf<4;++mf){
        int row = wm*64 + mf*16 + l15;
        int ch = (kc*4 + g) ^ (row & 7);
        bfr[mf] = *(const bf16x8*)(lx + row*KB + ch*8);
      }
#pragma unroll
      for(int nf=0;nf<NF;++nf)
#pragma unroll
        for(int mf=0;mf<4;++mf)
          acc[nf][mf] = __builtin_amdgcn_mfma_f32_16x16x32_bf16(af[nf], bfr[mf], acc[nf][mf], 0, 0, 0);
    }
    __syncthreads();
  }

#pragma unroll
  for(int mf=0;mf<4;++mf){
    int m = bm*128 + wm*64 + mf*16 + l15;
#pragma unroll
    for(int nf=0;nf<NF;++nf){
      int n = bn*NB + wn*(16*NF) + nf*16 + g*4;
      f32x4 v = acc[nf][mf];
      f32x4 bz = *(const f32x4*)(p.bias + n);
      v = v + bz;
      if constexpr(EPI == 0){            // QKV: Q (cols<1024) *= L2E/8, bf16
        float sc = (n < 1024) ? 0.125f*L2E : 1.0f;
        s16x4 o;
#pragma unroll
        for(int e=0;e<4;++e) o[e] = (short)f2bf(v[e]*sc);
        *(s16x4*)(p.outB + (size_t)m*p.Nmat + n) = o;
      } else if constexpr(EPI == 1){     // out-proj: zero padded rows, +x, f32
        int b_ = m >> 11, q = m & 2047;
        f32x4 r = *(const f32x4*)(p.resid + (size_t)m*1024 + n);
        if(q >= p.lens[b_]){ v[0]=0.f; v[1]=0.f; v[2]=0.f; v[3]=0.f; }
        v = v + r;
        *(f32x4*)(p.outF + (size_t)m*p.Nmat + n) = v;
      } else if constexpr(EPI == 2){     // FFN1: quick-gelu, bf16
        s16x4 o;
#pragma unroll
        for(int e=0;e<4;++e){
          float sg = v[e]*__builtin_amdgcn_rcpf(1.f + exp2f(-1.702f*L2E*v[e]));
          o[e] = (short)f2bf(sg);
        }
        *(s16x4*)(p.outB + (size_t)m*p.Nmat + n) = o;
      } else {                           // FFN2: +x1, f32 out
        f32x4 r = *(const f32x4*)(p.resid + (size_t)m*p.Nmat + n);
        v = v + r;
        *(f32x4*)(p.outF + (size_t)m*p.Nmat + n) = v;
      }
    }
  }
}

// ---------------- V repack: qkv V-part [n][hd] -> vt [b,h,hd,n] -------------
__global__ __launch_bounds__(256)
void repack_vt(const unsigned short* qkv, unsigned short* vt){
  __shared__ unsigned short t[64*80];
  int id = blockIdx.x;
  int bh = id >> 5, nt = id & 31;
  int b = bh >> 4, h = bh & 15;
  int tid = threadIdx.x;
  int r = tid >> 2, c0 = (tid & 3)*16;
  const unsigned short* src = qkv + ((size_t)(b*2048 + nt*64 + r)*3072 + 2048 + h*64 + c0);
  bf16x8 v0 = *(const bf16x8*)(src);
  bf16x8 v1 = *(const bf16x8*)(src + 8);
  *(bf16x8*)(t + r*80 + c0) = v0;
  *(bf16x8*)(t + r*80 + c0 + 8) = v1;
  __syncthreads();
#pragma unroll
  for(int cc=0; cc<2; ++cc){
    int ci = cc*256 + tid;
    int hd = ci >> 3, nc = (ci & 7)*8;
    bf16x8 o;
#pragma unroll
    for(int i=0;i<8;++i) o[i] = (short)t[(nc+i)*80 + hd];
    *(bf16x8*)(vt + ((size_t)(bh*64 + hd)*2048 + nt*64 + nc)) = o;
  }
}

// ---------------- flash attention fwd (round-15 structure, cbuf epilogue) ---
// grid 512; complementary-qt pairing (j and j+256 share a CU); Q pre-scaled
// by L2E/8 in QKV epilogue. 2-buf LDS, prefetch before compute, __syncthreads.
// Epilogue writes c = 2^-m / l directly (replaces prep_c).
__global__ __launch_bounds__(256)
void attn_flash(const unsigned short* qkv, const unsigned short* vt,
                unsigned short* attnO, float* cbuf, const int* lens)
{
  __shared__ unsigned short lk[2][64*64];
  __shared__ unsigned short lv[2][64*64];
  int id = blockIdx.x;
  int jj = id & 255;
  int bh = jj & 31;
  int qt = (id < 256) ? (15 - (jj >> 5)) : (jj >> 5);
  int b = bh >> 4, h = bh & 15;
  int tid = threadIdx.x, lane = tid & 63, wave = tid >> 6;
  int hi = lane >> 5, l31 = lane & 31;
  int q = qt*128 + wave*32 + l31;
  int len_b = lens[b];

  const unsigned short* qptr = qkv + ((size_t)(b*2048 + q)*3072 + h*64);
  bf16x8 qf[4];
#pragma unroll
  for(int ks=0;ks<4;++ks) qf[ks] = *(const bf16x8*)(qptr + ks*16 + hi*8);

  const unsigned short* srcK[2]; const unsigned short* srcV[2];
  int dof[2];
#pragma unroll
  for(int i=0;i<2;++i){
    int slot = i*256 + tid, row = slot >> 3, c = slot & 7, cs = c ^ (row & 7);
    srcK[i] = qkv + ((size_t)(b*2048 + row)*3072 + 1024 + h*64) + cs*8;
    srcV[i] = vt + ((size_t)(bh*64 + row)*2048) + cs*8;
    dof[i] = (i*256 + (tid & 192))*8;
  }

  f32x16 oacc[2];
#pragma unroll
  for(int a=0;a<2;++a)
#pragma unroll
    for(int e=0;e<16;++e) oacc[a][e] = 0.f;
  float mcur = -1e30f, lsum = 0.f;
  int ktmax = qt*2 + 1;

  // prologue: stage tile 0 into buf 0
#pragma unroll
  for(int i=0;i<2;++i){
    gl_lds16(srcK[i], &lk[0][dof[i]]);
    gl_lds16(srcV[i], &lv[0][dof[i]]);
    srcK[i] += (size_t)64*3072;
    srcV[i] += 64;
  }
  __syncthreads();

  int buf = 0;
  for(int kt=0; kt<=ktmax; ++kt){
    if(kt < ktmax){                      // prefetch t+1 before compute of t
#pragma unroll
      for(int i=0;i<2;++i){
        gl_lds16(srcK[i], &lk[buf^1][dof[i]]);
        gl_lds16(srcV[i], &lv[buf^1][dof[i]]);
        srcK[i] += (size_t)64*3072;
        srcV[i] += 64;
      }
    }

    f32x16 s2[2];
#pragma unroll
    for(int kb=0;kb<2;++kb){
      f32x16 a;
#pragma unroll
      for(int e=0;e<16;++e) a[e] = 0.f;
      int row = kb*32 + l31;
#pragma unroll
      for(int ks=0;ks<4;++ks){
        int ch = (ks*2 + hi) ^ (row & 7);
        bf16x8 kf = *(const bf16x8*)(&lk[buf][0] + row*64 + ch*8);
        a = __builtin_amdgcn_mfma_f32_32x32x16_bf16(kf, qf[ks], a, 0, 0, 0);
      }
      s2[kb] = a;
    }

    // masking + max: 4-acc tree (dep depth ~9 instead of 32)
    float m0=-1e30f, m1=-1e30f, m2=-1e30f, m3=-1e30f;
    bool full = (kt*64 + 63 < qt*128 + wave*32) && (kt*64 + 64 <= len_b);
    if(full){
#pragma unroll
      for(int kb=0;kb<2;++kb)
#pragma unroll
        for(int r=0;r<16;r+=4){
          m0=fmaxf(m0,s2[kb][r+0]); m1=fmaxf(m1,s2[kb][r+1]);
          m2=fmaxf(m2,s2[kb][r+2]); m3=fmaxf(m3,s2[kb][r+3]);
        }
    } else {
#pragma unroll
      for(int kb=0;kb<2;++kb)
#pragma unroll
        for(int r=0;r<16;++r){
          int key = kt*64 + kb*32 + (r&3) + 8*(r>>2) + 4*hi;
          bool ok = (key == q) || ((key < q) && (key < len_b));
          float tv = ok ? s2[kb][r] : -1e30f;
          s2[kb][r] = tv;
          if((r&3)==0) m0=fmaxf(m0,tv); else if((r&3)==1) m1=fmaxf(m1,tv);
          else if((r&3)==2) m2=fmaxf(m2,tv); else m3=fmaxf(m3,tv);
        }
    }
    float tmax = fmaxf(fmaxf(m0,m1), fmaxf(m2,m3));
    tmax = fmaxf(tmax, __shfl_xor(tmax, 32, 64));

    if(!__all(tmax <= mcur + 8.f)){      // defer-max (T13)
      float mnew = fmaxf(mcur, tmax);
      float fsc = exp2f(mcur - mnew);
      lsum *= fsc;
#pragma unroll
      for(int a=0;a<2;++a)
#pragma unroll
        for(int e=0;e<16;++e) oacc[a][e] *= fsc;
      mcur = mnew;
    }
    float r0=0.f, r1=0.f, r2=0.f, r3=0.f;
#pragma unroll
    for(int kb=0;kb<2;++kb)
#pragma unroll
      for(int r=0;r<16;++r){
        float pv = exp2f(s2[kb][r] - mcur);
        s2[kb][r] = pv;
        if((r&3)==0) r0+=pv; else if((r&3)==1) r1+=pv;
        else if((r&3)==2) r2+=pv; else r3+=pv;
      }
    float rsum = (r0+r1)+(r2+r3);
    rsum += __shfl_xor(rsum, 32, 64);
    lsum += rsum;

#pragma unroll
    for(int ks=0;ks<4;++ks){
      int kb = ks >> 1, r0i = (ks & 1)*8;
      unsigned int a0 = cvt_pk_bf16(s2[kb][r0i+0], s2[kb][r0i+1]);
      unsigned int a1 = cvt_pk_bf16(s2[kb][r0i+2], s2[kb][r0i+3]);
      unsigned int a2 = cvt_pk_bf16(s2[kb][r0i+4], s2[kb][r0i+5]);
      unsigned int a3 = cvt_pk_bf16(s2[kb][r0i+6], s2[kb][r0i+7]);
      unsigned int b0 = __shfl_xor(a0, 32, 64);
      unsigned int b1 = __shfl_xor(a1, 32, 64);
      unsigned int b2 = __shfl_xor(a2, 32, 64);
      unsigned int b3 = __shfl_xor(a3, 32, 64);
      union { u32x4 u; bf16x8 s8; } pw;
      pw.u[0] = hi ? b2 : a0;
      pw.u[1] = hi ? b3 : a1;
      pw.u[2] = hi ? a2 : b0;
      pw.u[3] = hi ? a3 : b1;
#pragma unroll
      for(int af=0;af<2;++af){
        int vrow = af*32 + l31;
        int ch = (ks*2 + hi) ^ (vrow & 7);
        bf16x8 vf = *(const bf16x8*)(&lv[buf][0] + vrow*64 + ch*8);
        oacc[af] = __builtin_amdgcn_mfma_f32_32x32x16_bf16(vf, pw.s8, oacc[af], 0, 0, 0);
      }
    }
    __syncthreads();                     // implicit vmcnt(0): prefetch landed
    buf ^= 1;
  }

  float rl = __builtin_amdgcn_rcpf(lsum);
  if(hi == 0){
    cbuf[(size_t)bh*2048 + q] = exp2f(-mcur) * rl;   // c = 2^-m / l
  }
  unsigned short* obase = attnO + ((size_t)(b*2048 + q)*1024 + h*64);
#pragma unroll
  for(int af=0;af<2;++af)
#pragma unroll
    for(int grp=0; grp<4; ++grp){
      int hd0 = af*32 + grp*8 + hi*4;
      u32x2 st;
      st[0] = cvt_pk_bf16(oacc[af][grp*4+0]*rl, oacc[af][grp*4+1]*rl);
      st[1] = cvt_pk_bf16(oacc[af][grp*4+2]*rl, oacc[af][grp*4+3]*rl);
      *(u32x2*)(obase + hd0) = st;
    }
}

// ---------------- weights = mean_h softmax probs (recompute QK^T) -----------
__global__ __launch_bounds__(256)
void attn_weights(const unsigned short* qkv, const float* cbuf,
                  float* wout, const int* lens)
{
  int id = blockIdx.x;
  int kt = id & 15, qt = (id >> 4) & 15, b = id >> 8;
  int tid = threadIdx.x;
  float* wtile = wout + ((size_t)(b*2048 + qt*128))*2048 + kt*128;

  if(kt > qt){                            // strictly-upper tile: zeros
    f32x4 z; z[0]=0.f; z[1]=0.f; z[2]=0.f; z[3]=0.f;
#pragma unroll
    for(int i=0;i<8;++i){
      float* p = wtile + (size_t)(i*16 + (tid>>4))*2048 + (tid&15)*8;
      *(f32x4*)p = z; *(f32x4*)(p+4) = z;
    }
    return;
  }

  __shared__ unsigned short lk[2][128*64];
  __shared__ unsigned short lq[2][128*64];
  int lane = tid & 63, wave = tid >> 6, hi = lane >> 5, l31 = lane & 31;
  int len_b = lens[b];
  int q_abs = qt*128 + wave*32 + l31;

  const float* cb = cbuf + (size_t)(b*16)*2048 + q_abs;
  float ccs[16];
#pragma unroll
  for(int h=0;h<16;++h) ccs[h] = cb[(size_t)h*2048];

  const unsigned short* srcK[4]; const unsigned short* srcQ[4]; int dA[4];
#pragma unroll
  for(int i=0;i<4;++i){
    int d = i*256 + tid, row = d >> 3, c = d & 7, cs = c ^ (row & 7);
    srcK[i] = qkv + ((size_t)(b*2048 + kt*128 + row)*3072 + 1024) + cs*8;
    srcQ[i] = qkv + ((size_t)(b*2048 + qt*128 + row)*3072) + cs*8;
    dA[i] = d*8;
  }

  float wacc[4][16];
#pragma unroll
  for(int ksub=0;ksub<4;++ksub)
#pragma unroll
    for(int r=0;r<16;++r) wacc[ksub][r] = 0.f;

#pragma unroll
  for(int i=0;i<4;++i){
    gl_lds16(srcK[i], &lk[0][dA[i]]);
    gl_lds16(srcQ[i], &lq[0][dA[i]]);
  }
  __syncthreads();

  int buf = 0;
  for(int h=0;h<16;++h){
    if(h < 15){
#pragma unroll
      for(int i=0;i<4;++i){
        gl_lds16(srcK[i] + (h+1)*64, &lk[buf^1][dA[i]]);
        gl_lds16(srcQ[i] + (h+1)*64, &lq[buf^1][dA[i]]);
      }
    }
    bf16x8 qf[4];
#pragma unroll
    for(int ks=0;ks<4;++ks){
      int row = wave*32 + l31;
      int ch = (ks*2 + hi) ^ (row & 7);
      qf[ks] = *(const bf16x8*)(&lq[buf][0] + row*64 + ch*8);
    }
    float cc = ccs[h];
#pragma unroll
    for(int ksub=0;ksub<4;++ksub){
      f32x16 sc;
#pragma unroll
      for(int e=0;e<16;++e) sc[e] = 0.f;
#pragma unroll
      for(int ks=0;ks<4;++ks){
        int row = ksub*32 + l31;
        int ch = (ks*2 + hi) ^ (row & 7);
        bf16x8 kf = *(const bf16x8*)(&lk[buf][0] + row*64 + ch*8);
        sc = __builtin_amdgcn_mfma_f32_32x32x16_bf16(kf, qf[ks], sc, 0, 0, 0);
      }
#pragma unroll
      for(int r=0;r<16;++r)
        wacc[ksub][r] += exp2f(sc[r]) * cc;  // Q pre-scaled by L2E
    }
    __syncthreads();
    buf ^= 1;
  }

#pragma unroll
  for(int ksub=0;ksub<4;++ksub)
#pragma unroll
    for(int rg=0;rg<4;++rg){
      f32x4 v;
#pragma unroll
      for(int e=0;e<4;++e){
        int key_abs = kt*128 + ksub*32 + rg*8 + hi*4 + e;
        bool ok = (key_abs == q_abs) || ((key_abs < q_abs) && (key_abs < len_b));
        v[e] = ok ? wacc[ksub][rg*4 + e]*0.0625f : 0.f;
      }
      *(f32x4*)(wtile + (size_t)(wave*32 + l31)*2048 + ksub*32 + rg*8 + hi*4) = v;
    }
}

// ---------------- launch --------------------------------------------------
extern "C" void kernel_launch(void* const* d_in, const int* in_sizes, int n_in,
                              void* d_out, int out_size, void* d_ws, size_t ws_size,
                              hipStream_t stream)
{
  const float* x     = (const float*)d_in[0];
  const unsigned char* mask = (const unsigned char*)d_in[1];
  const float* ln1g  = (const float*)d_in[2];
  const float* ln1b  = (const float*)d_in[3];
  const float* w_in  = (const float*)d_in[4];
  const float* b_in  = (const float*)d_in[5];
  const float* w_out = (const float*)d_in[6];
  const float* b_out = (const float*)d_in[7];
  const float* ln2g  = (const float*)d_in[8];
  const float* ln2b  = (const float*)d_in[9];
  const float* w1    = (const float*)d_in[10];
  const float* b1    = (const float*)d_in[11];
  const float* w2    = (const float*)d_in[12];
  const float* b2    = (const float*)d_in[13];
  float* out = (float*)d_out;

  char* ws = (char*)d_ws;
  size_t off = 0;
  auto take = [&](size_t bytes)->char*{
    char* p = ws + off; off += (bytes + 255) & ~(size_t)255; return p;
  };
  int* lens            = (int*)take(256);
  unsigned short* wq   = (unsigned short*)take((size_t)3072*1024*2);   // contig:
  unsigned short* wo   = (unsigned short*)take((size_t)1024*1024*2);   //  wq,wo,
  unsigned short* w1c  = (unsigned short*)take((size_t)4096*1024*2);   //  w1c,w2c
  unsigned short* w2c  = (unsigned short*)take((size_t)1024*4096*2);
  unsigned short* xn   = (unsigned short*)take((size_t)4096*1024*2);
  unsigned short* qkv  = (unsigned short*)take((size_t)4096*3072*2);
  unsigned short* vt   = (unsigned short*)take((size_t)32*64*2048*2);
  float* cbuf          = (float*)take((size_t)32*2048*4);
  unsigned short* aO   = (unsigned short*)take((size_t)4096*1024*2);
  float* x1            = (float*)take((size_t)4096*1024*4);
  unsigned short* hmid = (unsigned short*)take((size_t)4096*4096*2);

  prep_len<<<1,256,0,stream>>>(mask, lens);
  conv_all<<<12288,256,0,stream>>>(w_in, w_out, w1, w2, wq);
  ln_k<<<4096,256,0,stream>>>(x, ln1g, ln1b, xn);

  GemmP p1{wq, xn, 3072, 1024, b_in, nullptr, nullptr, nullptr, qkv};
  gemm_k<0,128,64><<<768,256,0,stream>>>(p1);
  repack_vt<<<1024,256,0,stream>>>(qkv, vt);
  attn_flash<<<512,256,0,stream>>>(qkv, vt, aO, cbuf, lens);
  attn_weights<<<512,256,0,stream>>>(qkv, cbuf, out + 4194304, lens);

  GemmP p2{wo, aO, 1024, 1024, b_out, x, lens, x1, nullptr};
  gemm_k<1,64,128><<<512,256,0,stream>>>(p2);
  ln_k<<<4096,256,0,stream>>>(x1, ln2g, ln2b, xn);
  GemmP p3{w1c, xn, 4096, 1024, b1, nullptr, nullptr, nullptr, hmid};
  gemm_k<2,128,64><<<1024,256,0,stream>>>(p3);
  GemmP p4{w2c, hmid, 1024, 4096, b2, x1, nullptr, out, nullptr};
  gemm_k<3,64,128><<<512,256,0,stream>>>(p4);
}